// Round 6
// baseline (236.157 us; speedup 1.0000x reference)
//
#include <hip/hip_runtime.h>
#include <math.h>

// Problem constants (fixed by reference)
#define BB 4
#define NN 512
#define DD 128
#define HH 8
#define KK 16

typedef float f4 __attribute__((ext_vector_type(4)));

__device__ __forceinline__ f4 ntload4(const float* p) {
    return __builtin_nontemporal_load(reinterpret_cast<const f4*>(p));
}

// ---------------------------------------------------------------------------
// Kernel 1: Q/K/V projections (verified since R1).
// Store as [b][n][p] with p = h*16 + k; Q pre-scaled by 1/sqrt(16) = 0.25.
// ---------------------------------------------------------------------------
__global__ __launch_bounds__(128) void proj_kernel(
    const float* __restrict__ q,
    const float* __restrict__ Wq,
    const float* __restrict__ Wk,
    const float* __restrict__ Wv,
    float* __restrict__ Qs,
    float* __restrict__ Kp,
    float* __restrict__ Vp)
{
    __shared__ float qrow[DD];
    const int bn = blockIdx.x;
    const int t = threadIdx.x;          // 0..127 -> p = h*16+k
    qrow[t] = q[(size_t)bn * DD + t];
    __syncthreads();
    const int h = t >> 4;
    const int k = t & 15;
    const float* wq = Wq + (size_t)h * DD * KK + k;   // stride KK over d
    const float* wk = Wk + (size_t)h * DD * KK + k;
    const float* wv = Wv + (size_t)h * DD * KK + k;
    float aq = 0.f, ak = 0.f, av = 0.f;
#pragma unroll 16
    for (int d = 0; d < DD; ++d) {
        const float x = qrow[d];
        aq = fmaf(x, wq[(size_t)d * KK], aq);
        ak = fmaf(x, wk[(size_t)d * KK], ak);
        av = fmaf(x, wv[(size_t)d * KK], av);
    }
    Qs[(size_t)bn * DD + t] = aq * 0.25f;   // norm = 1/sqrt(KEY_DIM=16)
    Kp[(size_t)bn * DD + t] = ak;
    Vp[(size_t)bn * DD + t] = av;
}

// ---------------------------------------------------------------------------
// Kernel 2: V transpose Vp[b][m][p] -> Vt[b][p][m] (verified R4).
// ---------------------------------------------------------------------------
__global__ __launch_bounds__(256) void vt_kernel(
    const float* __restrict__ Vp, float* __restrict__ Vt)
{
    __shared__ float tile[64][129];
    const int b  = blockIdx.x >> 3;
    const int m0 = (blockIdx.x & 7) * 64;
    const int t  = threadIdx.x;
    const float* src = Vp + ((size_t)b * NN + m0) * DD;
#pragma unroll
    for (int j = 0; j < 8; ++j) {
        const int idx4 = t + j * 256;
        const float4 v = *(const float4*)(src + (size_t)idx4 * 4);
        const int r = idx4 >> 5, c = (idx4 & 31) * 4;
        tile[r][c] = v.x; tile[r][c+1] = v.y; tile[r][c+2] = v.z; tile[r][c+3] = v.w;
    }
    __syncthreads();
    const int m = t & 63;
#pragma unroll
    for (int p0 = 0; p0 < 128; p0 += 4) {
        const int p = p0 + (t >> 6);
        Vt[((size_t)b * DD + p) * NN + m0 + m] = tile[m][p];
    }
}

// ---------------------------------------------------------------------------
// Kernel 3: QK^T -> QKT[b][n][h][m] (verified R4).
// ---------------------------------------------------------------------------
__global__ __launch_bounds__(256) void qkt_kernel(
    const float* __restrict__ Qs, const float* __restrict__ Kp,
    float* __restrict__ QKT)
{
    const int b    = blockIdx.x >> 7;
    const int n4   = blockIdx.x & 127;
    const int tid  = threadIdx.x;
    const int wave = tid >> 6;
    const int lane = tid & 63;
    const int sub  = lane >> 4;
    const int dc   = lane & 15;
    const int d0   = dc * 8;

    float qf[4][8];
#pragma unroll
    for (int j = 0; j < 4; ++j) {
        const float* qp = Qs + ((size_t)b * NN + n4 * 4 + j) * DD + d0;
        const float4 a = *(const float4*)qp;
        const float4 c = *(const float4*)(qp + 4);
        qf[j][0]=a.x; qf[j][1]=a.y; qf[j][2]=a.z; qf[j][3]=a.w;
        qf[j][4]=c.x; qf[j][5]=c.y; qf[j][6]=c.z; qf[j][7]=c.w;
    }
    const float* kbase = Kp + (size_t)b * NN * DD;
    for (int i = 0; i < 32; ++i) {
        const int m = wave * 128 + i * 4 + sub;
        const float* kp = kbase + (size_t)m * DD + d0;
        const float4 k0 = *(const float4*)kp;
        const float4 k1 = *(const float4*)(kp + 4);
        float kr[8];
        kr[0]=k0.x; kr[1]=k0.y; kr[2]=k0.z; kr[3]=k0.w;
        kr[4]=k1.x; kr[5]=k1.y; kr[6]=k1.z; kr[7]=k1.w;
#pragma unroll
        for (int j = 0; j < 4; ++j) {
            float s = kr[0] * qf[j][0];
#pragma unroll
            for (int u = 1; u < 8; ++u) s = fmaf(kr[u], qf[j][u], s);
            s += __shfl_xor(s, 1);
            if ((dc & 1) == 0)
                QKT[(((size_t)b * NN + n4 * 4 + j) * HH + (dc >> 1)) * NN + m] = s;
        }
    }
}

// ---------------------------------------------------------------------------
// Kernel 4: PURE streaming edge-bias GEMV, copy-ordered.
// Wave W (of 8192) processes chunk C = W + p*8192, p = 0..31; chunk = 2 KB =
// 4 e-rows. At any instant the device reads one contiguous ~16 MB window
// (like the 6.3 TB/s copy ubench) -> few open-row streams per HBM channel.
// No barriers, no LDS. Fold = R2's verified 16-lane fold. 1 store / 2 KB.
// ---------------------------------------------------------------------------
__global__ __launch_bounds__(256) void ebias_kernel(
    const float* __restrict__ e,
    const float* __restrict__ Ev,      // [H][D]
    float* __restrict__ E)             // [bn][h][m]
{
    const int tid  = threadIdx.x;
    const int wave = tid >> 6;
    const int lane = tid & 63;
    const int sub  = lane >> 4;          // row within chunk (4 rows/chunk)
    const int dc   = lane & 15;          // 8-float chunk along d
    const int d0   = dc * 8;
    const int W    = blockIdx.x * 4 + wave;   // 0..8191

    float ev[HH][8];
#pragma unroll
    for (int h = 0; h < HH; ++h) {
        const float4 a = *(const float4*)(Ev + h * DD + d0);
        const float4 c = *(const float4*)(Ev + h * DD + d0 + 4);
        ev[h][0]=a.x; ev[h][1]=a.y; ev[h][2]=a.z; ev[h][3]=a.w;
        ev[h][4]=c.x; ev[h][5]=c.y; ev[h][6]=c.z; ev[h][7]=c.w;
    }
    const bool hi8 = (dc & 8) != 0;
    const bool hi4 = (dc & 4) != 0;
    const bool hi2 = (dc & 2) != 0;
    const int laneoff = sub * DD + d0;   // within-chunk float offset

    auto do_chunk = [&](const f4 e0, const f4 e1, const int C) {
        float er[8];
        er[0]=e0.x; er[1]=e0.y; er[2]=e0.z; er[3]=e0.w;
        er[4]=e1.x; er[5]=e1.y; er[6]=e1.z; er[7]=e1.w;
        float acc[HH];
#pragma unroll
        for (int h = 0; h < HH; ++h) {
            float s = er[0] * ev[h][0];
#pragma unroll
            for (int u = 1; u < 8; ++u) s = fmaf(er[u], ev[h][u], s);
            acc[h] = s;
        }
        float t4[4];
#pragma unroll
        for (int j = 0; j < 4; ++j) {
            const float keep = hi8 ? acc[j + 4] : acc[j];
            const float send = hi8 ? acc[j]     : acc[j + 4];
            t4[j] = keep + __shfl_xor(send, 8);
        }
        float t2[2];
#pragma unroll
        for (int j = 0; j < 2; ++j) {
            const float keep = hi4 ? t4[j + 2] : t4[j];
            const float send = hi4 ? t4[j]     : t4[j + 2];
            t2[j] = keep + __shfl_xor(send, 4);
        }
        float w;
        {
            const float keep = hi2 ? t2[1] : t2[0];
            const float send = hi2 ? t2[0] : t2[1];
            w = keep + __shfl_xor(send, 2);
        }
        w += __shfl_xor(w, 1);
        if ((dc & 1) == 0) {
            const int bn = C >> 7;
            const int m  = ((C & 127) << 2) + sub;
            E[((size_t)bn * HH + (dc >> 1)) * NN + m] = w;
        }
    };

#define LDE(B0, B1, p) { const float* _p = e + (size_t)(W + (p) * 8192) * 512 + laneoff; \
                         B0 = ntload4(_p); B1 = ntload4(_p + 4); }

    f4 A0, A1, B0, B1, C0, C1;
    LDE(A0, A1, 0); LDE(B0, B1, 1);
    for (int p = 0; p < 30; p += 3) {          // 2-ahead, static buffer names
        LDE(C0, C1, p + 2); do_chunk(A0, A1, W + p * 8192);
        LDE(A0, A1, p + 3); do_chunk(B0, B1, W + (p + 1) * 8192);
        LDE(B0, B1, p + 4); do_chunk(C0, C1, W + (p + 2) * 8192);
    }
    do_chunk(A0, A1, W + 30 * 8192); do_chunk(B0, B1, W + 31 * 8192);
#undef LDE
}

// ---------------------------------------------------------------------------
// Kernel 5: softmax + PV + out-projection (R4 phase-2 verbatim; compat read
// from global E+QKT, both coalesced [bn][h][m]).
// ---------------------------------------------------------------------------
__global__ __launch_bounds__(256) void softmax_kernel(
    const float* __restrict__ E,       // [bn][h][m]
    const float* __restrict__ QKT,     // [bn][h][m]
    const float* __restrict__ Vt,      // [B][P][M], p = h*16+v
    const float* __restrict__ Wout,    // [P][E]
    float* __restrict__ out)           // [B][N][E]
{
    __shared__ float headsv[HH * KK];
    const int bn   = blockIdx.x;
    const int b    = bn >> 9;
    const int tid  = threadIdx.x;
    const int wave = tid >> 6;
    const int lane = tid & 63;

#pragma unroll
    for (int hh = 0; hh < 2; ++hh) {
        const int h = wave * 2 + hh;
        const float* eb   = E   + ((size_t)bn * HH + h) * NN;
        const float* qk   = QKT + ((size_t)bn * HH + h) * NN;
        const float* vrow = Vt + ((size_t)b * DD + h * KK) * NN;

        float s[8];
#pragma unroll
        for (int i = 0; i < 8; ++i)
            s[i] = eb[lane + i * 64] + qk[lane + i * 64];

        float mx = s[0];
#pragma unroll
        for (int i = 1; i < 8; ++i) mx = fmaxf(mx, s[i]);
#pragma unroll
        for (int mask = 1; mask <= 32; mask <<= 1)
            mx = fmaxf(mx, __shfl_xor(mx, mask));

        float pr[8], psum = 0.f;
#pragma unroll
        for (int i = 0; i < 8; ++i) { pr[i] = __expf(s[i] - mx); psum += pr[i]; }

        float av[KK];
#pragma unroll
        for (int v = 0; v < KK; ++v) av[v] = 0.f;
#pragma unroll
        for (int v = 0; v < KK; ++v) {
            const float* vp = vrow + (size_t)v * NN + lane;
#pragma unroll
            for (int i = 0; i < 8; ++i)
                av[v] = fmaf(pr[i], vp[i * 64], av[v]);
        }
#pragma unroll
        for (int mask = 1; mask <= 32; mask <<= 1)
            psum += __shfl_xor(psum, mask);

        const bool s5 = (lane & 32) != 0;
        float a8[8];
#pragma unroll
        for (int j = 0; j < 8; ++j) {
            const float keep = s5 ? av[j + 8] : av[j];
            const float send = s5 ? av[j]     : av[j + 8];
            a8[j] = keep + __shfl_xor(send, 32);
        }
        const bool s4 = (lane & 16) != 0;
        float a4[4];
#pragma unroll
        for (int j = 0; j < 4; ++j) {
            const float keep = s4 ? a8[j + 4] : a8[j];
            const float send = s4 ? a8[j]     : a8[j + 4];
            a4[j] = keep + __shfl_xor(send, 16);
        }
        const bool s3 = (lane & 8) != 0;
        float a2[2];
#pragma unroll
        for (int j = 0; j < 2; ++j) {
            const float keep = s3 ? a4[j + 2] : a4[j];
            const float send = s3 ? a4[j]     : a4[j + 2];
            a2[j] = keep + __shfl_xor(send, 8);
        }
        const bool s2 = (lane & 4) != 0;
        float a1;
        {
            const float keep = s2 ? a2[1] : a2[0];
            const float send = s2 ? a2[0] : a2[1];
            a1 = keep + __shfl_xor(send, 4);
        }
        a1 += __shfl_xor(a1, 2);
        a1 += __shfl_xor(a1, 1);
        if ((lane & 3) == 0)
            headsv[h * KK + (lane >> 2)] = a1 / psum;
    }
    __syncthreads();

    if (tid < DD) {
        float o = 0.f;
#pragma unroll 8
        for (int p = 0; p < HH * KK; ++p)
            o = fmaf(headsv[p], Wout[(size_t)p * DD + tid], o);
        out[(size_t)bn * DD + tid] = o;
    }
}

extern "C" void kernel_launch(void* const* d_in, const int* in_sizes, int n_in,
                              void* d_out, int out_size, void* d_ws, size_t ws_size,
                              hipStream_t stream) {
    const float* q    = (const float*)d_in[0];
    const float* e    = (const float*)d_in[1];
    const float* Wq   = (const float*)d_in[2];
    const float* Wk   = (const float*)d_in[3];
    const float* Wv   = (const float*)d_in[4];
    const float* Ev   = (const float*)d_in[5];
    const float* Wout = (const float*)d_in[6];
    float* out = (float*)d_out;

    float* Qs  = (float*)d_ws;                    // [B][N][128]   1 MB
    float* Kp  = Qs  + (size_t)BB * NN * DD;      // [B][N][128]   1 MB
    float* Vp  = Kp  + (size_t)BB * NN * DD;      // [B][N][128]   1 MB
    float* Vt  = Vp  + (size_t)BB * NN * DD;      // [B][128][N]   1 MB
    float* QKT = Vt  + (size_t)BB * DD * NN;      // [bn][h][m]    33.5 MB
    float* E   = QKT + (size_t)BB * NN * HH * NN; // [bn][h][m]    33.5 MB

    proj_kernel<<<BB * NN, 128, 0, stream>>>(q, Wq, Wk, Wv, Qs, Kp, Vp);
    vt_kernel<<<BB * 8, 256, 0, stream>>>(Vp, Vt);
    qkt_kernel<<<BB * 128, 256, 0, stream>>>(Qs, Kp, QKT);
    ebias_kernel<<<2048, 256, 0, stream>>>(e, Ev, E);
    softmax_kernel<<<BB * NN, 256, 0, stream>>>(E, QKT, Vt, Wout, out);
}

// Round 7
// 216.253 us; speedup vs baseline: 1.0920x; 1.0920x over previous
//
#include <hip/hip_runtime.h>
#include <math.h>

// Problem constants (fixed by reference)
#define BB 4
#define NN 512
#define DD 128
#define HH 8
#define KK 16

typedef float f4     __attribute__((ext_vector_type(4)));
typedef short bf16x8 __attribute__((ext_vector_type(8)));

__device__ __forceinline__ f4 ntload4(const float* p) {
    return __builtin_nontemporal_load(reinterpret_cast<const f4*>(p));
}

// pack 8 f32 (truncate-to-bf16) -> bf16x8
__device__ __forceinline__ unsigned pack2(float lo, float hi) {
    return (__float_as_uint(hi) & 0xFFFF0000u) | (__float_as_uint(lo) >> 16);
}
__device__ __forceinline__ bf16x8 packb(const f4 a, const f4 b) {
    union { unsigned u[4]; bf16x8 v; } r;
    r.u[0] = pack2(a.x, a.y);
    r.u[1] = pack2(a.z, a.w);
    r.u[2] = pack2(b.x, b.y);
    r.u[3] = pack2(b.z, b.w);
    return r.v;
}
__device__ __forceinline__ f4 hif(const f4 x) {   // truncate each elem to bf16 precision
    f4 r;
    r.x = __uint_as_float(__float_as_uint(x.x) & 0xFFFF0000u);
    r.y = __uint_as_float(__float_as_uint(x.y) & 0xFFFF0000u);
    r.z = __uint_as_float(__float_as_uint(x.z) & 0xFFFF0000u);
    r.w = __uint_as_float(__float_as_uint(x.w) & 0xFFFF0000u);
    return r;
}

// ---------------------------------------------------------------------------
// Kernel 1: Q/K/V projections (verified since R1).
// ---------------------------------------------------------------------------
__global__ __launch_bounds__(128) void proj_kernel(
    const float* __restrict__ q,
    const float* __restrict__ Wq,
    const float* __restrict__ Wk,
    const float* __restrict__ Wv,
    float* __restrict__ Qs,
    float* __restrict__ Kp,
    float* __restrict__ Vp)
{
    __shared__ float qrow[DD];
    const int bn = blockIdx.x;
    const int t = threadIdx.x;          // 0..127 -> p = h*16+k
    qrow[t] = q[(size_t)bn * DD + t];
    __syncthreads();
    const int h = t >> 4;
    const int k = t & 15;
    const float* wq = Wq + (size_t)h * DD * KK + k;
    const float* wk = Wk + (size_t)h * DD * KK + k;
    const float* wv = Wv + (size_t)h * DD * KK + k;
    float aq = 0.f, ak = 0.f, av = 0.f;
#pragma unroll 16
    for (int d = 0; d < DD; ++d) {
        const float x = qrow[d];
        aq = fmaf(x, wq[(size_t)d * KK], aq);
        ak = fmaf(x, wk[(size_t)d * KK], ak);
        av = fmaf(x, wv[(size_t)d * KK], av);
    }
    Qs[(size_t)bn * DD + t] = aq * 0.25f;   // norm = 1/sqrt(KEY_DIM=16)
    Kp[(size_t)bn * DD + t] = ak;
    Vp[(size_t)bn * DD + t] = av;
}

// ---------------------------------------------------------------------------
// Kernel 2: V transpose Vp[b][m][p] -> Vt[b][p][m] (verified R4).
// ---------------------------------------------------------------------------
__global__ __launch_bounds__(256) void vt_kernel(
    const float* __restrict__ Vp, float* __restrict__ Vt)
{
    __shared__ float tile[64][129];
    const int b  = blockIdx.x >> 3;
    const int m0 = (blockIdx.x & 7) * 64;
    const int t  = threadIdx.x;
    const float* src = Vp + ((size_t)b * NN + m0) * DD;
#pragma unroll
    for (int j = 0; j < 8; ++j) {
        const int idx4 = t + j * 256;
        const float4 v = *(const float4*)(src + (size_t)idx4 * 4);
        const int r = idx4 >> 5, c = (idx4 & 31) * 4;
        tile[r][c] = v.x; tile[r][c+1] = v.y; tile[r][c+2] = v.z; tile[r][c+3] = v.w;
    }
    __syncthreads();
    const int m = t & 63;
#pragma unroll
    for (int p0 = 0; p0 < 128; p0 += 4) {
        const int p = p0 + (t >> 6);
        Vt[((size_t)b * DD + p) * NN + m0 + m] = tile[m][p];
    }
}

// ---------------------------------------------------------------------------
// Kernel 3: QK^T -> QKT[b][n][h][m] (verified R4).
// ---------------------------------------------------------------------------
__global__ __launch_bounds__(256) void qkt_kernel(
    const float* __restrict__ Qs, const float* __restrict__ Kp,
    float* __restrict__ QKT)
{
    const int b    = blockIdx.x >> 7;
    const int n4   = blockIdx.x & 127;
    const int tid  = threadIdx.x;
    const int wave = tid >> 6;
    const int lane = tid & 63;
    const int sub  = lane >> 4;
    const int dc   = lane & 15;
    const int d0   = dc * 8;

    float qf[4][8];
#pragma unroll
    for (int j = 0; j < 4; ++j) {
        const float* qp = Qs + ((size_t)b * NN + n4 * 4 + j) * DD + d0;
        const float4 a = *(const float4*)qp;
        const float4 c = *(const float4*)(qp + 4);
        qf[j][0]=a.x; qf[j][1]=a.y; qf[j][2]=a.z; qf[j][3]=a.w;
        qf[j][4]=c.x; qf[j][5]=c.y; qf[j][6]=c.z; qf[j][7]=c.w;
    }
    const float* kbase = Kp + (size_t)b * NN * DD;
    for (int i = 0; i < 32; ++i) {
        const int m = wave * 128 + i * 4 + sub;
        const float* kp = kbase + (size_t)m * DD + d0;
        const float4 k0 = *(const float4*)kp;
        const float4 k1 = *(const float4*)(kp + 4);
        float kr[8];
        kr[0]=k0.x; kr[1]=k0.y; kr[2]=k0.z; kr[3]=k0.w;
        kr[4]=k1.x; kr[5]=k1.y; kr[6]=k1.z; kr[7]=k1.w;
#pragma unroll
        for (int j = 0; j < 4; ++j) {
            float s = kr[0] * qf[j][0];
#pragma unroll
            for (int u = 1; u < 8; ++u) s = fmaf(kr[u], qf[j][u], s);
            s += __shfl_xor(s, 1);
            if ((dc & 1) == 0)
                QKT[(((size_t)b * NN + n4 * 4 + j) * HH + (dc >> 1)) * NN + m] = s;
        }
    }
}

// ---------------------------------------------------------------------------
// Kernel 4 (R7): edge-bias via MFMA, split hi/lo bf16 (near-fp32 accuracy).
// One wave = one 16-row x 128-d e-tile (8 KB). All 8 dwordx4 loads issued
// up-front (max MLP, zero coupling); 12 chained mfma_f32_16x16x32_bf16;
// D-frag cols = head (lane&15), rows = m0+(lane>>4)*4+i -> coalesced f4 store.
// Zero shuffles / LDS / barriers.
// ---------------------------------------------------------------------------
__global__ __launch_bounds__(256) void ebias_kernel(
    const float* __restrict__ e,
    const float* __restrict__ Ev,      // [H][D]
    float* __restrict__ E)             // [bn][h][m]
{
    const int tid  = threadIdx.x;
    const int wave = tid >> 6;
    const int lane = tid & 63;
    const int W    = blockIdx.x * 4 + wave;   // tile id 0..65535
    const int bn   = W >> 5;                  // 0..2047
    const int m0   = (W & 31) << 4;           // 0..496
    const int row  = lane & 15;               // A row within tile / B,D col
    const int kg   = lane >> 4;               // k-subgroup (8 floats)

    // ---- B fragments from Ev: B[k][n] = Ev[n][k], slices s: k = s*32+kg*8+i
    bf16x8 Bhi[4], Blo[4];
#pragma unroll
    for (int s = 0; s < 4; ++s) {
        f4 b0 = {0.f,0.f,0.f,0.f}, b1 = {0.f,0.f,0.f,0.f};
        if (row < HH) {
            const float* p = Ev + row * DD + s * 32 + kg * 8;
            b0 = *(const f4*)p; b1 = *(const f4*)(p + 4);
        }
        Bhi[s] = packb(b0, b1);
        const f4 l0 = b0 - hif(b0), l1 = b1 - hif(b1);
        Blo[s] = packb(l0, l1);
    }

    // ---- issue ALL e loads for this tile (lane: row, k-chunk kg; slice s)
    const float* ab = e + ((size_t)bn * NN + m0 + row) * DD + kg * 8;
    const f4 a00 = ntload4(ab +   0), a01 = ntload4(ab +   4);   // s=0
    const f4 a10 = ntload4(ab +  32), a11 = ntload4(ab +  36);   // s=1
    const f4 a20 = ntload4(ab +  64), a21 = ntload4(ab +  68);   // s=2
    const f4 a30 = ntload4(ab +  96), a31 = ntload4(ab + 100);   // s=3

    f4 acc = {0.f, 0.f, 0.f, 0.f};
#define SLICE(A0, A1, s) {                                            \
        const bf16x8 ahi = packb(A0, A1);                             \
        const f4 lo0 = A0 - hif(A0), lo1 = A1 - hif(A1);              \
        const bf16x8 alo = packb(lo0, lo1);                           \
        acc = __builtin_amdgcn_mfma_f32_16x16x32_bf16(alo, Bhi[s], acc, 0, 0, 0); \
        acc = __builtin_amdgcn_mfma_f32_16x16x32_bf16(ahi, Blo[s], acc, 0, 0, 0); \
        acc = __builtin_amdgcn_mfma_f32_16x16x32_bf16(ahi, Bhi[s], acc, 0, 0, 0); \
    }
    SLICE(a00, a01, 0);
    SLICE(a10, a11, 1);
    SLICE(a20, a21, 2);
    SLICE(a30, a31, 3);
#undef SLICE

    // ---- store: D col = row(=head), D rows = kg*4 + i -> m0+kg*4+i
    if (row < HH) {
        float* dst = E + ((size_t)bn * HH + row) * NN + m0 + kg * 4;
        *(f4*)dst = acc;
    }
}

// ---------------------------------------------------------------------------
// Kernel 5: softmax + PV + out-projection (verified R6).
// ---------------------------------------------------------------------------
__global__ __launch_bounds__(256) void softmax_kernel(
    const float* __restrict__ E,       // [bn][h][m]
    const float* __restrict__ QKT,     // [bn][h][m]
    const float* __restrict__ Vt,      // [B][P][M], p = h*16+v
    const float* __restrict__ Wout,    // [P][E]
    float* __restrict__ out)           // [B][N][E]
{
    __shared__ float headsv[HH * KK];
    const int bn   = blockIdx.x;
    const int b    = bn >> 9;
    const int tid  = threadIdx.x;
    const int wave = tid >> 6;
    const int lane = tid & 63;

#pragma unroll
    for (int hh = 0; hh < 2; ++hh) {
        const int h = wave * 2 + hh;
        const float* eb   = E   + ((size_t)bn * HH + h) * NN;
        const float* qk   = QKT + ((size_t)bn * HH + h) * NN;
        const float* vrow = Vt + ((size_t)b * DD + h * KK) * NN;

        float s[8];
#pragma unroll
        for (int i = 0; i < 8; ++i)
            s[i] = eb[lane + i * 64] + qk[lane + i * 64];

        float mx = s[0];
#pragma unroll
        for (int i = 1; i < 8; ++i) mx = fmaxf(mx, s[i]);
#pragma unroll
        for (int mask = 1; mask <= 32; mask <<= 1)
            mx = fmaxf(mx, __shfl_xor(mx, mask));

        float pr[8], psum = 0.f;
#pragma unroll
        for (int i = 0; i < 8; ++i) { pr[i] = __expf(s[i] - mx); psum += pr[i]; }

        float av[KK];
#pragma unroll
        for (int v = 0; v < KK; ++v) av[v] = 0.f;
#pragma unroll
        for (int v = 0; v < KK; ++v) {
            const float* vp = vrow + (size_t)v * NN + lane;
#pragma unroll
            for (int i = 0; i < 8; ++i)
                av[v] = fmaf(pr[i], vp[i * 64], av[v]);
        }
#pragma unroll
        for (int mask = 1; mask <= 32; mask <<= 1)
            psum += __shfl_xor(psum, mask);

        const bool s5 = (lane & 32) != 0;
        float a8[8];
#pragma unroll
        for (int j = 0; j < 8; ++j) {
            const float keep = s5 ? av[j + 8] : av[j];
            const float send = s5 ? av[j]     : av[j + 8];
            a8[j] = keep + __shfl_xor(send, 32);
        }
        const bool s4 = (lane & 16) != 0;
        float a4[4];
#pragma unroll
        for (int j = 0; j < 4; ++j) {
            const float keep = s4 ? a8[j + 4] : a8[j];
            const float send = s4 ? a8[j]     : a8[j + 4];
            a4[j] = keep + __shfl_xor(send, 16);
        }
        const bool s3 = (lane & 8) != 0;
        float a2[2];
#pragma unroll
        for (int j = 0; j < 2; ++j) {
            const float keep = s3 ? a4[j + 2] : a4[j];
            const float send = s3 ? a4[j]     : a4[j + 2];
            a2[j] = keep + __shfl_xor(send, 8);
        }
        const bool s2 = (lane & 4) != 0;
        float a1;
        {
            const float keep = s2 ? a2[1] : a2[0];
            const float send = s2 ? a2[0] : a2[1];
            a1 = keep + __shfl_xor(send, 4);
        }
        a1 += __shfl_xor(a1, 2);
        a1 += __shfl_xor(a1, 1);
        if ((lane & 3) == 0)
            headsv[h * KK + (lane >> 2)] = a1 / psum;
    }
    __syncthreads();

    if (tid < DD) {
        float o = 0.f;
#pragma unroll 8
        for (int p = 0; p < HH * KK; ++p)
            o = fmaf(headsv[p], Wout[(size_t)p * DD + tid], o);
        out[(size_t)bn * DD + tid] = o;
    }
}

extern "C" void kernel_launch(void* const* d_in, const int* in_sizes, int n_in,
                              void* d_out, int out_size, void* d_ws, size_t ws_size,
                              hipStream_t stream) {
    const float* q    = (const float*)d_in[0];
    const float* e    = (const float*)d_in[1];
    const float* Wq   = (const float*)d_in[2];
    const float* Wk   = (const float*)d_in[3];
    const float* Wv   = (const float*)d_in[4];
    const float* Ev   = (const float*)d_in[5];
    const float* Wout = (const float*)d_in[6];
    float* out = (float*)d_out;

    float* Qs  = (float*)d_ws;                    // [B][N][128]   1 MB
    float* Kp  = Qs  + (size_t)BB * NN * DD;      // [B][N][128]   1 MB
    float* Vp  = Kp  + (size_t)BB * NN * DD;      // [B][N][128]   1 MB
    float* Vt  = Vp  + (size_t)BB * NN * DD;      // [B][128][N]   1 MB
    float* QKT = Vt  + (size_t)BB * DD * NN;      // [bn][h][m]    33.5 MB
    float* E   = QKT + (size_t)BB * NN * HH * NN; // [bn][h][m]    33.5 MB

    proj_kernel<<<BB * NN, 128, 0, stream>>>(q, Wq, Wk, Wv, Qs, Kp, Vp);
    vt_kernel<<<BB * 8, 256, 0, stream>>>(Vp, Vt);
    qkt_kernel<<<BB * 128, 256, 0, stream>>>(Qs, Kp, QKT);
    ebias_kernel<<<BB * NN * NN / 64, 256, 0, stream>>>(e, Ev, E);  // 16384 blocks
    softmax_kernel<<<BB * NN, 256, 0, stream>>>(E, QKT, Vt, Wout, out);
}

// Round 8
// 196.993 us; speedup vs baseline: 1.1988x; 1.0978x over previous
//
#include <hip/hip_runtime.h>
#include <math.h>

// Problem constants (fixed by reference)
#define BB 4
#define NN 512
#define DD 128
#define HH 8
#define KK 16

typedef float f4 __attribute__((ext_vector_type(4)));

__device__ __forceinline__ f4 ntload4(const float* p) {
    return __builtin_nontemporal_load(reinterpret_cast<const f4*>(p));
}

// ---------------------------------------------------------------------------
// Kernel 1: Q/K/V projections (verified since R1).
// Store as [b][n][p] with p = h*16 + k; Q pre-scaled by 1/sqrt(16) = 0.25.
// ---------------------------------------------------------------------------
__global__ __launch_bounds__(128) void proj_kernel(
    const float* __restrict__ q,
    const float* __restrict__ Wq,
    const float* __restrict__ Wk,
    const float* __restrict__ Wv,
    float* __restrict__ Qs,
    float* __restrict__ Kp,
    float* __restrict__ Vp)
{
    __shared__ float qrow[DD];
    const int bn = blockIdx.x;
    const int t = threadIdx.x;          // 0..127 -> p = h*16+k
    qrow[t] = q[(size_t)bn * DD + t];
    __syncthreads();
    const int h = t >> 4;
    const int k = t & 15;
    const float* wq = Wq + (size_t)h * DD * KK + k;
    const float* wk = Wk + (size_t)h * DD * KK + k;
    const float* wv = Wv + (size_t)h * DD * KK + k;
    float aq = 0.f, ak = 0.f, av = 0.f;
#pragma unroll 16
    for (int d = 0; d < DD; ++d) {
        const float x = qrow[d];
        aq = fmaf(x, wq[(size_t)d * KK], aq);
        ak = fmaf(x, wk[(size_t)d * KK], ak);
        av = fmaf(x, wv[(size_t)d * KK], av);
    }
    Qs[(size_t)bn * DD + t] = aq * 0.25f;   // norm = 1/sqrt(KEY_DIM=16)
    Kp[(size_t)bn * DD + t] = ak;
    Vp[(size_t)bn * DD + t] = av;
}

// ---------------------------------------------------------------------------
// Kernel 2 (R8): fused QK^T + V-transpose (both depend only on proj).
// blocks 0..511   : qkt -> QKT[b][n][h][m]   (verified R4 logic)
// blocks 512..543 : vt  -> Vt[b][p][m]       (verified R4 logic)
// ---------------------------------------------------------------------------
__global__ __launch_bounds__(256) void prep_kernel(
    const float* __restrict__ Qs, const float* __restrict__ Kp,
    const float* __restrict__ Vp,
    float* __restrict__ QKT, float* __restrict__ Vt)
{
    __shared__ float tile[64][129];
    const int blk = blockIdx.x;
    const int tid = threadIdx.x;

    if (blk < 512) {                      // ---- QK^T ----
        const int b    = blk >> 7;
        const int n4   = blk & 127;
        const int wave = tid >> 6;
        const int lane = tid & 63;
        const int sub  = lane >> 4;
        const int dc   = lane & 15;
        const int d0   = dc * 8;

        float qf[4][8];
#pragma unroll
        for (int j = 0; j < 4; ++j) {
            const float* qp = Qs + ((size_t)b * NN + n4 * 4 + j) * DD + d0;
            const float4 a = *(const float4*)qp;
            const float4 c = *(const float4*)(qp + 4);
            qf[j][0]=a.x; qf[j][1]=a.y; qf[j][2]=a.z; qf[j][3]=a.w;
            qf[j][4]=c.x; qf[j][5]=c.y; qf[j][6]=c.z; qf[j][7]=c.w;
        }
        const float* kbase = Kp + (size_t)b * NN * DD;
        for (int i = 0; i < 32; ++i) {
            const int m = wave * 128 + i * 4 + sub;
            const float* kp = kbase + (size_t)m * DD + d0;
            const float4 k0 = *(const float4*)kp;
            const float4 k1 = *(const float4*)(kp + 4);
            float kr[8];
            kr[0]=k0.x; kr[1]=k0.y; kr[2]=k0.z; kr[3]=k0.w;
            kr[4]=k1.x; kr[5]=k1.y; kr[6]=k1.z; kr[7]=k1.w;
#pragma unroll
            for (int j = 0; j < 4; ++j) {
                float s = kr[0] * qf[j][0];
#pragma unroll
                for (int u = 1; u < 8; ++u) s = fmaf(kr[u], qf[j][u], s);
                s += __shfl_xor(s, 1);
                if ((dc & 1) == 0)
                    QKT[(((size_t)b * NN + n4 * 4 + j) * HH + (dc >> 1)) * NN + m] = s;
            }
        }
    } else {                              // ---- V transpose ----
        const int vb = blk - 512;
        const int b  = vb >> 3;
        const int m0 = (vb & 7) * 64;
        const float* src = Vp + ((size_t)b * NN + m0) * DD;
#pragma unroll
        for (int j = 0; j < 8; ++j) {
            const int idx4 = tid + j * 256;
            const float4 v = *(const float4*)(src + (size_t)idx4 * 4);
            const int r = idx4 >> 5, c = (idx4 & 31) * 4;
            tile[r][c] = v.x; tile[r][c+1] = v.y; tile[r][c+2] = v.z; tile[r][c+3] = v.w;
        }
        __syncthreads();
        const int m = tid & 63;
#pragma unroll
        for (int p0 = 0; p0 < 128; p0 += 4) {
            const int p = p0 + (tid >> 6);
            Vt[((size_t)b * DD + p) * NN + m0 + m] = tile[m][p];
        }
    }
}

// ---------------------------------------------------------------------------
// Kernel 3: fused edge-bias + softmax + PV + out-projection (R4-verified).
// m-loop = pure e-stream (nt loads: no L2/L3 allocation -> QKT/Vt stay
// resident), 3-buffer/2-ahead register prefetch, R2's 16-lane fold.
// ---------------------------------------------------------------------------
__global__ __launch_bounds__(256) void attn_kernel(
    const float* __restrict__ e,
    const float* __restrict__ Ev,      // [H][D]
    const float* __restrict__ QKT,     // [B][N][H][M]
    const float* __restrict__ Vt,      // [B][P][M], p = h*16+v
    const float* __restrict__ Wout,    // [P][E]
    float* __restrict__ out)           // [B][N][E]
{
    __shared__ float comp[HH][NN + 4];
    __shared__ float headsv[HH * KK];

    const int bn   = blockIdx.x;
    const int b    = bn >> 9;
    const int tid  = threadIdx.x;
    const int wave = tid >> 6;
    const int lane = tid & 63;
    const int sub  = lane >> 4;          // row within a pass (4 rows/pass)
    const int dc   = lane & 15;          // 8-float chunk
    const int d0   = dc * 8;

    float ev[HH][8];
#pragma unroll
    for (int h = 0; h < HH; ++h) {
        const float4 a = *(const float4*)(Ev + h * DD + d0);
        const float4 c = *(const float4*)(Ev + h * DD + d0 + 4);
        ev[h][0]=a.x; ev[h][1]=a.y; ev[h][2]=a.z; ev[h][3]=a.w;
        ev[h][4]=c.x; ev[h][5]=c.y; ev[h][6]=c.z; ev[h][7]=c.w;
    }

    const bool hi8 = (dc & 8) != 0;
    const bool hi4 = (dc & 4) != 0;
    const bool hi2 = (dc & 2) != 0;
    const float* epl = e + (size_t)bn * NN * DD
                         + (size_t)(wave * 128 + sub) * DD + d0;

    auto do_pass = [&](const f4 e0, const f4 e1, const int p) {
        float er[8];
        er[0]=e0.x; er[1]=e0.y; er[2]=e0.z; er[3]=e0.w;
        er[4]=e1.x; er[5]=e1.y; er[6]=e1.z; er[7]=e1.w;
        float acc[HH];
#pragma unroll
        for (int h = 0; h < HH; ++h) {
            float s = er[0] * ev[h][0];
#pragma unroll
            for (int u = 1; u < 8; ++u) s = fmaf(er[u], ev[h][u], s);
            acc[h] = s;
        }
        float t4[4];
#pragma unroll
        for (int j = 0; j < 4; ++j) {
            const float keep = hi8 ? acc[j + 4] : acc[j];
            const float send = hi8 ? acc[j]     : acc[j + 4];
            t4[j] = keep + __shfl_xor(send, 8);
        }
        float t2[2];
#pragma unroll
        for (int j = 0; j < 2; ++j) {
            const float keep = hi4 ? t4[j + 2] : t4[j];
            const float send = hi4 ? t4[j]     : t4[j + 2];
            t2[j] = keep + __shfl_xor(send, 4);
        }
        float w;
        {
            const float keep = hi2 ? t2[1] : t2[0];
            const float send = hi2 ? t2[0] : t2[1];
            w = keep + __shfl_xor(send, 2);
        }
        w += __shfl_xor(w, 1);
        if ((dc & 1) == 0) comp[dc >> 1][wave * 128 + p * 4 + sub] = w;
    };

#define LDE(B0, B1, p) { const float* _p = epl + (size_t)(p) * 512; \
                         B0 = ntload4(_p); B1 = ntload4(_p + 4); }

    f4 A0, A1, B0, B1, C0, C1;
    LDE(A0, A1, 0); LDE(B0, B1, 1);
    for (int p = 0; p < 30; p += 3) {          // 2-ahead, static names
        LDE(C0, C1, p + 2); do_pass(A0, A1, p);
        LDE(A0, A1, p + 3); do_pass(B0, B1, p + 1);
        LDE(B0, B1, p + 4); do_pass(C0, C1, p + 2);
    }
    do_pass(A0, A1, 30); do_pass(B0, B1, 31);
#undef LDE
    __syncthreads();

    // ---- softmax + PV: wave handles heads 2w, 2w+1 ----
#pragma unroll
    for (int hh = 0; hh < 2; ++hh) {
        const int h = wave * 2 + hh;
        const float* qk   = QKT + ((size_t)bn * HH + h) * NN;
        const float* vrow = Vt + ((size_t)b * DD + h * KK) * NN;

        float s[8];
#pragma unroll
        for (int i = 0; i < 8; ++i)
            s[i] = comp[h][lane + i * 64] + qk[lane + i * 64];

        float mx = s[0];
#pragma unroll
        for (int i = 1; i < 8; ++i) mx = fmaxf(mx, s[i]);
#pragma unroll
        for (int mask = 1; mask <= 32; mask <<= 1)
            mx = fmaxf(mx, __shfl_xor(mx, mask));

        float pr[8], psum = 0.f;
#pragma unroll
        for (int i = 0; i < 8; ++i) { pr[i] = __expf(s[i] - mx); psum += pr[i]; }

        float av[KK];
#pragma unroll
        for (int v = 0; v < KK; ++v) av[v] = 0.f;
#pragma unroll
        for (int v = 0; v < KK; ++v) {
            const float* vp = vrow + (size_t)v * NN + lane;
#pragma unroll
            for (int i = 0; i < 8; ++i)
                av[v] = fmaf(pr[i], vp[i * 64], av[v]);
        }
#pragma unroll
        for (int mask = 1; mask <= 32; mask <<= 1)
            psum += __shfl_xor(psum, mask);

        const bool s5 = (lane & 32) != 0;
        float a8[8];
#pragma unroll
        for (int j = 0; j < 8; ++j) {
            const float keep = s5 ? av[j + 8] : av[j];
            const float send = s5 ? av[j]     : av[j + 8];
            a8[j] = keep + __shfl_xor(send, 32);
        }
        const bool s4 = (lane & 16) != 0;
        float a4[4];
#pragma unroll
        for (int j = 0; j < 4; ++j) {
            const float keep = s4 ? a8[j + 4] : a8[j];
            const float send = s4 ? a8[j]     : a8[j + 4];
            a4[j] = keep + __shfl_xor(send, 16);
        }
        const bool s3 = (lane & 8) != 0;
        float a2[2];
#pragma unroll
        for (int j = 0; j < 2; ++j) {
            const float keep = s3 ? a4[j + 2] : a4[j];
            const float send = s3 ? a4[j]     : a4[j + 2];
            a2[j] = keep + __shfl_xor(send, 8);
        }
        const bool s2 = (lane & 4) != 0;
        float a1;
        {
            const float keep = s2 ? a2[1] : a2[0];
            const float send = s2 ? a2[0] : a2[1];
            a1 = keep + __shfl_xor(send, 4);
        }
        a1 += __shfl_xor(a1, 2);
        a1 += __shfl_xor(a1, 1);
        if ((lane & 3) == 0)
            headsv[h * KK + (lane >> 2)] = a1 / psum;
    }
    __syncthreads();

    if (tid < DD) {
        float o = 0.f;
#pragma unroll 8
        for (int p = 0; p < HH * KK; ++p)
            o = fmaf(headsv[p], Wout[(size_t)p * DD + tid], o);
        out[(size_t)bn * DD + tid] = o;
    }
}

extern "C" void kernel_launch(void* const* d_in, const int* in_sizes, int n_in,
                              void* d_out, int out_size, void* d_ws, size_t ws_size,
                              hipStream_t stream) {
    const float* q    = (const float*)d_in[0];
    const float* e    = (const float*)d_in[1];
    const float* Wq   = (const float*)d_in[2];
    const float* Wk   = (const float*)d_in[3];
    const float* Wv   = (const float*)d_in[4];
    const float* Ev   = (const float*)d_in[5];
    const float* Wout = (const float*)d_in[6];
    float* out = (float*)d_out;

    float* Qs  = (float*)d_ws;                    // [B][N][128]   1 MB
    float* Kp  = Qs  + (size_t)BB * NN * DD;      // [B][N][128]   1 MB
    float* Vp  = Kp  + (size_t)BB * NN * DD;      // [B][N][128]   1 MB
    float* Vt  = Vp  + (size_t)BB * NN * DD;      // [B][128][N]   1 MB
    float* QKT = Vt  + (size_t)BB * DD * NN;      // [b][n][h][m]  33.5 MB

    proj_kernel<<<BB * NN, 128, 0, stream>>>(q, Wq, Wk, Wv, Qs, Kp, Vp);
    prep_kernel<<<544, 256, 0, stream>>>(Qs, Kp, Vp, QKT, Vt);
    attn_kernel<<<BB * NN, 256, 0, stream>>>(e, Ev, QKT, Vt, Wout, out);
}